// Round 1
// baseline (37.212 us; speedup 1.0000x reference)
//
#include <hip/hip_runtime.h>

// Glycolysis RHS: [28,B] f32 concentrations (+38-elem vmax/km/keq) -> [27,B] f32 derivs.
// Pure elementwise map over B -> memory-bound. All divisions via v_rcp_f32 (approx,
// ~1ulp; tolerance is ~0.665 absolute so this is far inside budget).

__device__ __forceinline__ float rcpf(float x) { return __builtin_amdgcn_rcpf(x); }

#define SAT(s, k) ((s) * rcpf((k) + (s)))
#define INH(x, k) ((k) * rcpf((k) + (x)))

extern "C" __global__ void __launch_bounds__(256)
glyco_rhs(const float* __restrict__ conc,
          const float* __restrict__ vmax,
          const float* __restrict__ km,
          const float* __restrict__ keq,
          float* __restrict__ out,
          int B)
{
    const int i = blockIdx.x * blockDim.x + threadIdx.x;
    if (i >= B) return;

    // ---- load concentrations (each row is a coalesced stream) ----
    const float Glci  = conc[ 0 * B + i];
    const float Glco  = conc[ 1 * B + i];
    const float ATP   = conc[ 2 * B + i];
    const float ADP   = conc[ 3 * B + i];
    const float G6P   = conc[ 4 * B + i];
    const float T6P   = conc[ 5 * B + i];
    const float G1P   = conc[ 6 * B + i];
    const float F6P   = conc[ 7 * B + i];
    const float PI_   = conc[ 8 * B + i];
    const float TRE   = conc[ 9 * B + i];
    const float F16BP = conc[10 * B + i];
    const float AMP   = conc[11 * B + i];
    const float DHAP  = conc[12 * B + i];
    const float G3P   = conc[13 * B + i];
    const float NAD   = conc[14 * B + i];
    const float GLYC  = conc[15 * B + i];
    const float BPG   = conc[16 * B + i];
    const float NADH  = conc[17 * B + i];
    const float P3G   = conc[18 * B + i];
    const float P2G   = conc[19 * B + i];
    const float PEP   = conc[20 * B + i];
    const float PYR   = conc[21 * B + i];
    const float ETOH  = conc[22 * B + i];
    const float ACE   = conc[23 * B + i];
    const float IMP   = conc[24 * B + i];
    const float INO   = conc[25 * B + i];
    const float HYP   = conc[26 * B + i];
    const float GAP   = conc[27 * B + i];

    const float UDP = 0.07f;

    // ---- fluxes (vmax/km/keq indexed with literals -> scalar loads) ----
    const float v_GLT   = vmax[0] * (Glco - Glci * rcpf(keq[0])) * rcpf(km[0] + Glco + Glci);
    const float v_GLK   = vmax[1] * SAT(ATP, km[1]) * SAT(Glci, km[1]) * INH(ADP, km[1]) * INH(G6P, km[1]) * INH(T6P, km[1]);
    const float v_PGM1  = vmax[2] * (G1P - G6P * rcpf(keq[2])) * rcpf(km[2] + G1P + G6P);
    const float v_TPS1  = vmax[3] * SAT(G6P, km[3]) * SAT(UDP, km[3]) * INH(F6P, km[3]) * INH(PI_, km[3]);
    const float v_TPS2  = vmax[4] * SAT(T6P, km[4]) * INH(PI_, km[4]);
    const float v_NTH1  = vmax[5] * SAT(TRE, km[5]);
    const float v_PGI   = vmax[6] * SAT(F6P, km[6]) * INH(ATP, km[6]);
    const float v_PFK   = vmax[7] * SAT(ATP, km[7]) * SAT(Glci, km[7]) * INH(F16BP, km[7]) * (1.0f + AMP * rcpf(km[7]));
    const float v_ALD   = vmax[8] * SAT(F16BP, km[8]) * INH(F6P, km[8]) * INH(DHAP, km[8]);
    const float v_TPI   = vmax[9] * (G3P - G3P * rcpf(keq[9])) * rcpf(km[9] + G3P + G3P);
    const float v_G3PDH = vmax[10] * SAT(DHAP, km[10]) * SAT(NAD, km[10]) * INH(G3P, km[10]) * INH(G3P, km[10])
                        * INH(F16BP, km[10]) * INH(ATP, km[10]) * INH(ADP, km[10]);
    const float v_HOR2  = vmax[11] * SAT(G3P, km[11]) * INH(PI_, km[11]);
    const float v_GlycT = vmax[12] * SAT(GLYC, km[12]);
    const float v_GAPDH = vmax[13] * SAT(G3P, km[13]) * SAT(NAD, km[13]) * SAT(PI_, km[13]) * INH(BPG, km[13]) * INH(NADH, km[13]);
    const float v_PGK   = vmax[14] * (BPG * ADP - P3G * ATP * rcpf(keq[14]))
                        * rcpf((km[14] + BPG + P3G) * (km[14] + ADP + ATP));
    const float v_PGM   = vmax[15] * (P3G - P2G * rcpf(keq[15])) * rcpf(km[15] + P3G + P2G);
    const float v_ENO   = vmax[16] * (P2G - PEP * rcpf(keq[16])) * rcpf(km[16] + P2G + PEP);
    const float v_PYK   = vmax[17] * SAT(PEP, km[17]) * SAT(ADP, km[17]) * INH(ATP, km[17]) * (1.0f + F16BP * rcpf(km[17]));
    const float v_PDC   = vmax[18] * SAT(PYR, km[18]) * INH(PI_, km[18]);
    const float v_ADH   = vmax[19] * (NAD * ETOH - ACE * NADH * rcpf(keq[19]))
                        * rcpf((km[19] + NAD + NADH) * (km[19] + ETOH + ACE));
    const float v_EtohT = vmax[20] * SAT(ETOH, km[20]);
    const float v_ATPm  = vmax[21] * SAT(PI_, km[21]) * SAT(ADP, km[21]);
    const float v_ATPa  = vmax[22] * SAT(ATP, km[22]) * INH(ADP, km[22]);
    const float v_ADK1  = vmax[23] * (ADP * ADP - ATP * AMP * rcpf(keq[23]))
                        * rcpf(km[23] + ADP * ADP + ATP * AMP);
    const float v_vacPi = vmax[24] * SAT(PI_, km[24]);
    const float v_Amd1  = vmax[25] * SAT(AMP, km[25]) * INH(ATP, km[25]) * INH(PI_, km[25]);
    const float v_Ade   = vmax[26] * SAT(IMP, km[26]);
    const float v_Isn1  = vmax[27] * SAT(IMP, km[27]);
    const float v_Pnp1  = vmax[28] * SAT(INO, km[28]);
    const float v_Hpt1  = vmax[29] * SAT(HYP, km[29]);
    const float v_NADHm = vmax[30] * SAT(NADH, km[30]);
    const float s_G6P   = vmax[31] * SAT(G6P, km[31]);
    const float s_F6P   = vmax[32] * SAT(F6P, km[32]);
    const float s_GAP   = vmax[33] * SAT(GAP, km[33]);
    const float s_P3G   = vmax[34] * SAT(P3G, km[34]);
    const float s_PEP   = vmax[35] * SAT(PEP, km[35]);
    const float s_PYR   = vmax[36] * SAT(PYR, km[36]);
    const float s_ACE   = vmax[37] * SAT(ACE, km[37]);

    // ---- assemble RHS (reference stack order) ----
    out[ 0 * B + i] = -v_GLK + v_GLT + 2.0f * v_NTH1;                         // GLCi
    out[ 1 * B + i] = v_GLK - v_PGI + s_G6P + v_PGM1 - v_TPS1;                // G6P
    out[ 2 * B + i] = -v_PGM1 - 0.00031f;                                     // G1P
    out[ 3 * B + i] = v_TPS1 - v_TPS2;                                        // T6P
    out[ 4 * B + i] = v_TPS2 - v_NTH1;                                        // TRE
    out[ 5 * B + i] = -v_PFK + v_PGI + s_F6P;                                 // F6P
    out[ 6 * B + i] = v_PFK - v_ALD;                                          // F16BP
    out[ 7 * B + i] = v_ALD - v_GAPDH + v_TPI + s_GAP;                        // GAP
    out[ 8 * B + i] = v_ALD - v_TPI - v_G3PDH;                                // DHAP
    out[ 9 * B + i] = v_G3PDH - v_HOR2;                                       // G3P
    out[10 * B + i] = v_HOR2 - v_GlycT;                                       // GLYCEROL
    out[11 * B + i] = v_GAPDH - v_PGK;                                        // BPG
    out[12 * B + i] = v_PGK - v_PGM + s_P3G;                                  // P3G
    out[13 * B + i] = v_PGM - v_ENO;                                          // P2G
    out[14 * B + i] = v_ENO - v_PYK + s_PEP;                                  // PEP
    out[15 * B + i] = v_PYK - v_PDC + s_PYR;                                  // PYR
    out[16 * B + i] = v_PDC - v_ADH + s_ACE;                                  // ACE
    out[17 * B + i] = v_ADH - v_EtohT;                                        // ETOH
    out[18 * B + i] = v_ADK1 - v_GLK - v_ATPa - v_PFK + v_PGK + v_PYK - v_TPS1 + v_ATPm;   // ATP
    out[19 * B + i] = -2.0f * v_ADK1 + v_GLK + v_ATPa + v_PFK - v_PGK - v_PYK + v_TPS1 - v_ATPm; // ADP
    out[20 * B + i] = v_ADK1 - v_Amd1 + v_Ade;                                // AMP
    out[21 * B + i] = -v_GAPDH + v_ATPa + v_HOR2 + 2.0f * v_TPS1 + v_TPS2 - v_ATPm
                    + v_Isn1 - v_Pnp1 + v_vacPi - s_G6P - s_F6P - s_GAP - s_P3G - s_PEP;   // PI
    out[22 * B + i] = v_Amd1 - v_Ade + v_Hpt1 - v_Isn1;                       // IMP
    out[23 * B + i] = v_Isn1 - v_Pnp1;                                        // INO
    out[24 * B + i] = v_Pnp1 - v_Hpt1;                                        // HYP
    out[25 * B + i] = v_G3PDH - v_GAPDH + v_ADH + v_NADHm;                    // NAD
    out[26 * B + i] = -v_G3PDH + v_GAPDH - v_ADH - v_NADHm;                   // NADH
}

extern "C" void kernel_launch(void* const* d_in, const int* in_sizes, int n_in,
                              void* d_out, int out_size, void* d_ws, size_t ws_size,
                              hipStream_t stream) {
    const float* conc = (const float*)d_in[0];
    const float* vmax = (const float*)d_in[1];
    const float* km   = (const float*)d_in[2];
    const float* keq  = (const float*)d_in[3];
    float* out = (float*)d_out;

    const int B = in_sizes[0] / 28;
    const int block = 256;
    const int grid = (B + block - 1) / block;
    hipLaunchKernelGGL(glyco_rhs, dim3(grid), dim3(block), 0, stream,
                       conc, vmax, km, keq, out, B);
}